// Round 1
// baseline (1191.189 us; speedup 1.0000x reference)
//
#include <hip/hip_runtime.h>
#include <hip/hip_bf16.h>

#define T_SEQ 2048
#define CDIM 1024
#define NHEAD 16
#define HDIM 64
#define BATCH 2
#define EPSV 1e-5f
#define SCALE 0.125f

// ---------------- fp32 tiled GEMM: C[M,N] = A[M,K] @ W[K,N] ----------------
// BM=BN=64, BK=16, 256 threads, 4x4 microtile per thread.
__global__ __launch_bounds__(256) void gemm_f32(const float* __restrict__ A,
                                                const float* __restrict__ W,
                                                float* __restrict__ C,
                                                int M, int N, int K) {
  __shared__ __align__(16) float As[16][68];  // [k][m], pad 68 for b128 alignment + banks
  __shared__ __align__(16) float Bs[16][64];  // [k][n]
  const int tid = threadIdx.x;
  const int tx = tid & 15, ty = tid >> 4;
  const int m0 = blockIdx.y * 64, n0 = blockIdx.x * 64;
  const int ar = tid >> 4, ac = tid & 15;   // A tile load: row group / k col
  const int br = tid >> 6, bc = tid & 63;   // B tile load
  float acc[4][4] = {};
  for (int k0 = 0; k0 < K; k0 += 16) {
#pragma unroll
    for (int i = 0; i < 4; ++i)
      As[ac][ar + 16 * i] = A[(size_t)(m0 + ar + 16 * i) * K + k0 + ac];
#pragma unroll
    for (int i = 0; i < 4; ++i)
      Bs[br + 4 * i][bc] = W[(size_t)(k0 + br + 4 * i) * N + n0 + bc];
    __syncthreads();
#pragma unroll
    for (int kk = 0; kk < 16; ++kk) {
      float4 a4 = *(const float4*)&As[kk][ty * 4];
      float4 b4 = *(const float4*)&Bs[kk][tx * 4];
      const float av[4] = {a4.x, a4.y, a4.z, a4.w};
      const float bv[4] = {b4.x, b4.y, b4.z, b4.w};
#pragma unroll
      for (int i = 0; i < 4; ++i)
#pragma unroll
        for (int j = 0; j < 4; ++j)
          acc[i][j] += av[i] * bv[j];
    }
    __syncthreads();
  }
#pragma unroll
  for (int i = 0; i < 4; ++i) {
    float4 r = make_float4(acc[i][0], acc[i][1], acc[i][2], acc[i][3]);
    *(float4*)&C[(size_t)(m0 + ty * 4 + i) * N + n0 + tx * 4] = r;
  }
}

// ---------------- RMSNorm over D=64 segments, Q and K in place ----------------
__global__ __launch_bounds__(256) void rmsnorm_qk(float* __restrict__ Q,
                                                  float* __restrict__ K,
                                                  const float* __restrict__ qw,
                                                  const float* __restrict__ kw) {
  const int lane = threadIdx.x & 63;
  const size_t seg = (size_t)blockIdx.x * 4 + (threadIdx.x >> 6);
  const size_t off = seg * 64 + lane;
  float q = Q[off];
  float s = q * q;
#pragma unroll
  for (int m = 1; m < 64; m <<= 1) s += __shfl_xor(s, m);
  Q[off] = q * rsqrtf(s * (1.0f / 64.0f) + EPSV) * qw[lane];
  float k = K[off];
  float s2 = k * k;
#pragma unroll
  for (int m = 1; m < 64; m <<= 1) s2 += __shfl_xor(s2, m);
  K[off] = k * rsqrtf(s2 * (1.0f / 64.0f) + EPSV) * kw[lane];
}

// ---------------- flash attention fp32 ----------------
// block = 256 threads, one (b, h, 32-q-row tile); loop over 32-wide k tiles.
// epilogue: O = gate[h] * (att @ v) + v_residual
__global__ __launch_bounds__(256) void attn_fwd(const float* __restrict__ Q,
                                                const float* __restrict__ K,
                                                const float* __restrict__ V,
                                                const float* __restrict__ gate,
                                                float* __restrict__ O) {
  __shared__ __align__(16) float q_lds[32][68];
  __shared__ __align__(16) float k_lds[32][68];
  __shared__ __align__(16) float v_lds[32][68];
  __shared__ __align__(16) float s_lds[32][33];
  __shared__ float mrow[32], lrow[32], frow[32];

  const int qt = blockIdx.x, h = blockIdx.y, b = blockIdx.z;
  const int tid = threadIdx.x;
  const int q0 = qt * 32;
  const size_t rowbase = (size_t)(b * T_SEQ) * CDIM + h * HDIM;

  // load Q tile (32 rows x 64 cols of this head)
  {
    const int f = tid & 15, r0 = tid >> 4;
#pragma unroll
    for (int p = 0; p < 2; ++p) {
      int r = r0 + p * 16;
      *(float4*)&q_lds[r][f * 4] =
          *(const float4*)&Q[rowbase + (size_t)(q0 + r) * CDIM + f * 4];
    }
  }
  if (tid < 32) { mrow[tid] = -1e30f; lrow[tid] = 0.f; }
  float acc[8] = {};
  const int qi = tid & 31, dg = tid >> 5;  // PV ownership: row qi, dims dg*8..dg*8+7

  const int nkt = qt + 1;  // causal: only k-tiles with k0 <= q_max
  for (int kt = 0; kt < nkt; ++kt) {
    const int k0 = kt * 32;
    {  // stage K, V tiles
      const int f = tid & 15, r0 = tid >> 4;
#pragma unroll
      for (int p = 0; p < 2; ++p) {
        int r = r0 + p * 16;
        *(float4*)&k_lds[r][f * 4] =
            *(const float4*)&K[rowbase + (size_t)(k0 + r) * CDIM + f * 4];
        *(float4*)&v_lds[r][f * 4] =
            *(const float4*)&V[rowbase + (size_t)(k0 + r) * CDIM + f * 4];
      }
    }
    __syncthreads();
    {  // scores: thread -> (qg, qg+16) x (kg, kg+16)
      const int qg = tid >> 4;
      const int kg = tid & 15;
      float s00 = 0, s01 = 0, s10 = 0, s11 = 0;
#pragma unroll
      for (int f = 0; f < 16; ++f) {
        float4 qa = *(const float4*)&q_lds[qg][f * 4];
        float4 qb = *(const float4*)&q_lds[qg + 16][f * 4];
        float4 ka = *(const float4*)&k_lds[kg][f * 4];
        float4 kb = *(const float4*)&k_lds[kg + 16][f * 4];
        s00 += qa.x * ka.x + qa.y * ka.y + qa.z * ka.z + qa.w * ka.w;
        s01 += qa.x * kb.x + qa.y * kb.y + qa.z * kb.z + qa.w * kb.w;
        s10 += qb.x * ka.x + qb.y * ka.y + qb.z * ka.z + qb.w * ka.w;
        s11 += qb.x * kb.x + qb.y * kb.y + qb.z * kb.z + qb.w * kb.w;
      }
      const int qa_g = q0 + qg, qb_g = q0 + qg + 16;
      const int ka_g = k0 + kg, kb_g = k0 + kg + 16;
      s_lds[qg][kg]           = (ka_g <= qa_g) ? s00 * SCALE : -1e30f;
      s_lds[qg][kg + 16]      = (kb_g <= qa_g) ? s01 * SCALE : -1e30f;
      s_lds[qg + 16][kg]      = (ka_g <= qb_g) ? s10 * SCALE : -1e30f;
      s_lds[qg + 16][kg + 16] = (kb_g <= qb_g) ? s11 * SCALE : -1e30f;
    }
    __syncthreads();
    if (tid < 32) {  // online softmax update (serial wave-0; round-0 simplicity)
      const int r = tid;
      float mx = -1e30f;
#pragma unroll
      for (int kk = 0; kk < 32; ++kk) mx = fmaxf(mx, s_lds[r][kk]);
      const float mold = mrow[r];
      const float mnew = fmaxf(mold, mx);
      const float fac = __expf(mold - mnew);
      float sum = 0.f;
#pragma unroll
      for (int kk = 0; kk < 32; ++kk) {
        float p = __expf(s_lds[r][kk] - mnew);
        s_lds[r][kk] = p;
        sum += p;
      }
      mrow[r] = mnew;
      lrow[r] = lrow[r] * fac + sum;
      frow[r] = fac;
    }
    __syncthreads();
    {  // PV accumulate
      const float fac = frow[qi];
#pragma unroll
      for (int j = 0; j < 8; ++j) acc[j] *= fac;
#pragma unroll
      for (int kk = 0; kk < 32; ++kk) {
        const float p = s_lds[qi][kk];
        float4 va = *(const float4*)&v_lds[kk][dg * 8];
        float4 vb = *(const float4*)&v_lds[kk][dg * 8 + 4];
        acc[0] += p * va.x; acc[1] += p * va.y; acc[2] += p * va.z; acc[3] += p * va.w;
        acc[4] += p * vb.x; acc[5] += p * vb.y; acc[6] += p * vb.z; acc[7] += p * vb.w;
      }
    }
    __syncthreads();
  }
  {  // epilogue: normalize, gate, add value residual
    const float invl = 1.0f / lrow[qi];
    const float g = gate[h];
    const size_t base = rowbase + (size_t)(q0 + qi) * CDIM + dg * 8;
#pragma unroll
    for (int j = 0; j < 8; ++j)
      O[base + j] = acc[j] * invl * g + V[base + j];
  }
}

extern "C" void kernel_launch(void* const* d_in, const int* in_sizes, int n_in,
                              void* d_out, int out_size, void* d_ws, size_t ws_size,
                              hipStream_t stream) {
  const float* x    = (const float*)d_in[0];
  // d_in[1] = attention_mask (causal tril) — exploited structurally
  const float* Wq   = (const float*)d_in[2];
  const float* Wk   = (const float*)d_in[3];
  const float* Wv   = (const float*)d_in[4];
  const float* Wo   = (const float*)d_in[5];
  const float* qw   = (const float*)d_in[6];
  const float* kw   = (const float*)d_in[7];
  const float* gate = (const float*)d_in[8];
  float* out = (float*)d_out;

  const int M = BATCH * T_SEQ;  // 4096
  // workspace: Q, K, V, O buffers, each M*CDIM fp32 (total 64 MB)
  float* Qb = (float*)d_ws;
  float* Kb = Qb + (size_t)M * CDIM;
  float* Vb = Kb + (size_t)M * CDIM;
  float* Ob = Vb + (size_t)M * CDIM;

  dim3 gg(CDIM / 64, M / 64);
  gemm_f32<<<gg, 256, 0, stream>>>(x, Wq, Qb, M, CDIM, CDIM);
  gemm_f32<<<gg, 256, 0, stream>>>(x, Wk, Kb, M, CDIM, CDIM);
  gemm_f32<<<gg, 256, 0, stream>>>(x, Wv, Vb, M, CDIM, CDIM);
  rmsnorm_qk<<<(M * NHEAD) / 4, 256, 0, stream>>>(Qb, Kb, qw, kw);
  attn_fwd<<<dim3(T_SEQ / 32, NHEAD, BATCH), 256, 0, stream>>>(Qb, Kb, Vb, gate, Ob);
  gemm_f32<<<gg, 256, 0, stream>>>(Ob, Wo, out, M, CDIM, CDIM);
}

// Round 2
// 163.537 us; speedup vs baseline: 7.2839x; 7.2839x over previous
//
#include <hip/hip_runtime.h>

#define T_SEQ 2048
#define CDIM 1024
#define NHEAD 16
#define HDIM 64
#define BATCH 2
#define EPSV 1e-5f
#define SCALE 0.125f

typedef __attribute__((ext_vector_type(8))) short bf16x8;
typedef __attribute__((ext_vector_type(4))) float f32x4;

__device__ __forceinline__ float b2f(short s) {
  unsigned u = ((unsigned)(unsigned short)s) << 16;
  return __builtin_bit_cast(float, u);
}
__device__ __forceinline__ short f2b(float f) {
  unsigned u = __builtin_bit_cast(unsigned, f);
  unsigned r = (u + 0x7fffu + ((u >> 16) & 1u)) >> 16;
  return (short)r;
}

__device__ __forceinline__ void gld16(const void* g, void* l) {
  __builtin_amdgcn_global_load_lds((const __attribute__((address_space(1))) unsigned*)g,
                                   (__attribute__((address_space(3))) unsigned*)l, 16, 0, 0);
}

// Stage an 8 KB tile (64 rows x 128 B) global->LDS, linear LDS dest,
// pre-swizzled global source: byte-in-row ^= (row&7)<<4  (T2/rule-21 pattern).
__device__ __forceinline__ void stage_sw(short* lds, const char* gbase, int gstride,
                                         int w, int l) {
#pragma unroll
  for (int i = 0; i < 2; ++i) {
    int chunk = w * 2048 + i * 1024 + l * 16;
    int row = chunk >> 7;
    int bir = chunk & 127;
    const char* src = gbase + (size_t)row * gstride + (bir ^ ((row & 7) << 4));
    gld16(src, (char*)lds + (w * 2048 + i * 1024));
  }
}

// ---------------- convert x fp32 -> bf16 ----------------
__global__ __launch_bounds__(256) void cvt_x(const float* __restrict__ x,
                                             short* __restrict__ xb) {
  size_t i = ((size_t)blockIdx.x * 256 + threadIdx.x) * 8;
  float4 a = *(const float4*)&x[i];
  float4 b = *(const float4*)&x[i + 4];
  short4 lo, hi;
  lo.x = f2b(a.x); lo.y = f2b(a.y); lo.z = f2b(a.z); lo.w = f2b(a.w);
  hi.x = f2b(b.x); hi.y = f2b(b.y); hi.z = f2b(b.z); hi.w = f2b(b.w);
  *(short4*)&xb[i] = lo;
  *(short4*)&xb[i + 4] = hi;
}

// ---------------- transpose weights fp32 [K][N] -> bf16 [N][K], combined ----------------
__global__ __launch_bounds__(256) void transW(const float* __restrict__ Wq,
                                              const float* __restrict__ Wk,
                                              const float* __restrict__ Wv,
                                              const float* __restrict__ Wo,
                                              short* __restrict__ WT) {
  __shared__ float tile[64][65];
  const int z = blockIdx.z;
  const float* W = (z == 0) ? Wq : (z == 1) ? Wk : (z == 2) ? Wv : Wo;
  const int r0 = blockIdx.y * 64, c0 = blockIdx.x * 64;
  const int tr = threadIdx.x >> 4, tc4 = (threadIdx.x & 15) * 4;
#pragma unroll
  for (int i = 0; i < 4; ++i) {
    float4 v = *(const float4*)&W[(size_t)(r0 + tr + i * 16) * 1024 + c0 + tc4];
    tile[tr + i * 16][tc4 + 0] = v.x;
    tile[tr + i * 16][tc4 + 1] = v.y;
    tile[tr + i * 16][tc4 + 2] = v.z;
    tile[tr + i * 16][tc4 + 3] = v.w;
  }
  __syncthreads();
#pragma unroll
  for (int i = 0; i < 4; ++i) {
    int n = tr + i * 16;
    short4 o;
    o.x = f2b(tile[tc4 + 0][n]);
    o.y = f2b(tile[tc4 + 1][n]);
    o.z = f2b(tile[tc4 + 2][n]);
    o.w = f2b(tile[tc4 + 3][n]);
    *(short4*)&WT[((size_t)(z * 1024) + c0 + n) * 1024 + r0 + tc4] = o;
  }
}

// ---------------- bf16 MFMA GEMM: C[M,N] = A[M,K] @ Bt[N,K]^T ----------------
// BM=128, BK=32, 256 threads (4 waves 2x2), wave tile 64 x BN/2.
template <int BN, bool F32OUT>
__global__ __launch_bounds__(256) void gemm_bf16(const short* __restrict__ A,
                                                 const short* __restrict__ Bt,
                                                 void* __restrict__ Cv,
                                                 int M, int N, int K) {
  constexpr int NFR = BN / 32;
  __shared__ __attribute__((aligned(16))) short As[128 * 32];
  __shared__ __attribute__((aligned(16))) short Bs[BN * 32];
  const int tid = threadIdx.x;
  const int w = tid >> 6, l = tid & 63;
  const int g = l >> 4, c = l & 15;
  const int wm = w >> 1, wn = w & 1;
  const int m0 = blockIdx.y * 128, n0 = blockIdx.x * BN;
  const char* Ab = (const char*)A;
  const char* Bb = (const char*)Bt;
  f32x4 acc[4][NFR];
#pragma unroll
  for (int mt = 0; mt < 4; ++mt)
#pragma unroll
    for (int nt = 0; nt < NFR; ++nt) {
      f32x4 z = {0.f, 0.f, 0.f, 0.f};
      acc[mt][nt] = z;
    }
  for (int k0 = 0; k0 < K; k0 += 32) {
#pragma unroll
    for (int i = 0; i < 2; ++i) {
      int chunk = w * 2048 + i * 1024 + l * 16;
      int row = chunk >> 6, bir = chunk & 63;
      gld16(Ab + ((size_t)(m0 + row) * K + k0) * 2 + bir, (char*)As + (w * 2048 + i * 1024));
    }
#pragma unroll
    for (int i = 0; i < BN / 64; ++i) {
      int chunk = w * (BN * 16) + i * 1024 + l * 16;
      int row = chunk >> 6, bir = chunk & 63;
      gld16(Bb + ((size_t)(n0 + row) * K + k0) * 2 + bir, (char*)Bs + (w * (BN * 16) + i * 1024));
    }
    __syncthreads();
    bf16x8 a[4], bf[NFR];
#pragma unroll
    for (int mt = 0; mt < 4; ++mt)
      a[mt] = *(const bf16x8*)&As[(wm * 64 + mt * 16 + c) * 32 + g * 8];
#pragma unroll
    for (int nt = 0; nt < NFR; ++nt)
      bf[nt] = *(const bf16x8*)&Bs[(wn * (BN / 2) + nt * 16 + c) * 32 + g * 8];
#pragma unroll
    for (int mt = 0; mt < 4; ++mt)
#pragma unroll
      for (int nt = 0; nt < NFR; ++nt)
        acc[mt][nt] = __builtin_amdgcn_mfma_f32_16x16x32_bf16(a[mt], bf[nt], acc[mt][nt], 0, 0, 0);
    __syncthreads();
  }
  if constexpr (F32OUT) {
    float* C = (float*)Cv;
#pragma unroll
    for (int mt = 0; mt < 4; ++mt)
#pragma unroll
      for (int nt = 0; nt < NFR; ++nt)
#pragma unroll
        for (int r = 0; r < 4; ++r)
          C[(size_t)(m0 + wm * 64 + mt * 16 + 4 * g + r) * N + n0 + wn * (BN / 2) + nt * 16 + c] =
              acc[mt][nt][r];
  } else {
    short* C = (short*)Cv;
#pragma unroll
    for (int mt = 0; mt < 4; ++mt)
#pragma unroll
      for (int nt = 0; nt < NFR; ++nt)
#pragma unroll
        for (int r = 0; r < 4; ++r)
          C[(size_t)(m0 + wm * 64 + mt * 16 + 4 * g + r) * N + n0 + wn * (BN / 2) + nt * 16 + c] =
              f2b(acc[mt][nt][r]);
  }
}

// ---------------- RMSNorm on bf16 Q,K inside QKV buffer (row stride 3072) ----------------
// Q gets SCALE folded in.
__global__ __launch_bounds__(256) void rmsnorm_qk(short* __restrict__ QKV,
                                                  const float* __restrict__ qw,
                                                  const float* __restrict__ kw) {
  const int l = threadIdx.x & 63;
  const int seg = blockIdx.x * 4 + (threadIdx.x >> 6);
  const int row = seg >> 4, h = seg & 15;
  const size_t qo = (size_t)row * 3072 + h * 64 + l;
  float q = b2f(QKV[qo]);
  float s = q * q;
#pragma unroll
  for (int m = 1; m < 64; m <<= 1) s += __shfl_xor(s, m);
  QKV[qo] = f2b(q * rsqrtf(s * (1.0f / 64.0f) + EPSV) * qw[l] * SCALE);
  const size_t ko = qo + 1024;
  float k = b2f(QKV[ko]);
  float s2 = k * k;
#pragma unroll
  for (int m = 1; m < 64; m <<= 1) s2 += __shfl_xor(s2, m);
  QKV[ko] = f2b(k * rsqrtf(s2 * (1.0f / 64.0f) + EPSV) * kw[l]);
}

// ---------------- V transpose: QKV's V slice [t][h*64+d] -> VT [b,h,d,t] ----------------
__global__ __launch_bounds__(256) void vt_kernel(const short* __restrict__ QKV,
                                                 short* __restrict__ VT) {
  const int w = threadIdx.x >> 6, l = threadIdx.x & 63;
  const int t0 = blockIdx.x * 32 + w * 8;
  const int h = blockIdx.y, b = blockIdx.z;
  short v[8];
#pragma unroll
  for (int j = 0; j < 8; ++j)
    v[j] = QKV[(size_t)(b * T_SEQ + t0 + j) * 3072 + 2048 + h * 64 + l];
  short* dst = VT + ((size_t)(b * NHEAD + h) * 64 + l) * T_SEQ + t0;
  *(bf16x8*)dst = *(bf16x8*)v;
}

// ---------------- MFMA flash attention ----------------
// 256 thr / 4 waves; block = (b,h,64 q rows); k-tiles of 64.
// S^T = K_tile @ Q^T  (wave w owns q-cols w*16..+15); softmax per q is lane-local
// + shfl_xor(16,32); P staged per-wave in LDS [q][k]; OUT^T = V^T @ P^T from VT tile.
__global__ __launch_bounds__(256) void attn_fwd(const short* __restrict__ QKV,
                                                const short* __restrict__ VT,
                                                const float* __restrict__ gate,
                                                short* __restrict__ Ob) {
  __shared__ __attribute__((aligned(16))) short Qs[64 * 64];
  __shared__ __attribute__((aligned(16))) short Ks[64 * 64];
  __shared__ __attribute__((aligned(16))) short Vs[64 * 64];
  __shared__ __attribute__((aligned(16))) short Ps[4][16][72];

  const int bid = blockIdx.x;
  const int flat = (bid & 7) * 128 + (bid >> 3);  // XCD-contiguous chunks
  const int qt = 31 - (flat & 31);                // big blocks first
  const int bh = flat >> 5;
  const int h = bh & 15, b = bh >> 4;
  const int q0 = qt * 64;
  const int tid = threadIdx.x;
  const int w = tid >> 6, l = tid & 63;
  const int g = l >> 4, c = l & 15;

  const char* qkb = (const char*)QKV;
  const char* qbase = qkb + ((size_t)(b * T_SEQ + q0) * 3072 + h * 64) * 2;
  const char* vtb = (const char*)VT + ((size_t)(b * NHEAD + h) * 64) * T_SEQ * 2;

  stage_sw(Qs, qbase, 3072 * 2, w, l);
  stage_sw(Ks, qkb + ((size_t)(b * T_SEQ) * 3072 + 1024 + h * 64) * 2, 3072 * 2, w, l);
  stage_sw(Vs, vtb, T_SEQ * 2, w, l);
  __syncthreads();

  bf16x8 qf[2];
  {
    const int row = w * 16 + c;
#pragma unroll
    for (int ks = 0; ks < 2; ++ks)
      qf[ks] = *(const bf16x8*)&Qs[row * 64 + ((ks * 32 + g * 8) ^ ((row & 7) << 3))];
  }

  f32x4 oacc[4];
#pragma unroll
  for (int dt = 0; dt < 4; ++dt) {
    f32x4 z = {0.f, 0.f, 0.f, 0.f};
    oacc[dt] = z;
  }
  float mold = -1e30f, lsum = 0.f;

  for (int kt = 0; kt <= qt; ++kt) {
    f32x4 sacc[4];
#pragma unroll
    for (int mt = 0; mt < 4; ++mt) {
      f32x4 z = {0.f, 0.f, 0.f, 0.f};
      sacc[mt] = z;
    }
#pragma unroll
    for (int mt = 0; mt < 4; ++mt) {
      const int row = mt * 16 + c;
#pragma unroll
      for (int ks = 0; ks < 2; ++ks) {
        bf16x8 kf = *(const bf16x8*)&Ks[row * 64 + ((ks * 32 + g * 8) ^ ((row & 7) << 3))];
        sacc[mt] = __builtin_amdgcn_mfma_f32_16x16x32_bf16(kf, qf[ks], sacc[mt], 0, 0, 0);
      }
    }
    if (kt == qt) {  // diagonal tile causal mask: krow > qrow -> -inf
#pragma unroll
      for (int mt = 0; mt < 4; ++mt)
#pragma unroll
        for (int r = 0; r < 4; ++r)
          if (mt * 16 + 4 * g + r > w * 16 + c) sacc[mt][r] = -1e30f;
    }
    // online softmax (per q-col c; reduce over k: in-lane 16 + xor16 + xor32)
    float tm = -1e30f;
#pragma unroll
    for (int mt = 0; mt < 4; ++mt)
#pragma unroll
      for (int r = 0; r < 4; ++r) tm = fmaxf(tm, sacc[mt][r]);
    tm = fmaxf(tm, __shfl_xor(tm, 16));
    tm = fmaxf(tm, __shfl_xor(tm, 32));
    const float mnew = fmaxf(mold, tm);
    const float fac = __expf(mold - mnew);
    float rs = 0.f;
#pragma unroll
    for (int mt = 0; mt < 4; ++mt) {
      float p0 = __expf(sacc[mt][0] - mnew);
      float p1 = __expf(sacc[mt][1] - mnew);
      float p2 = __expf(sacc[mt][2] - mnew);
      float p3 = __expf(sacc[mt][3] - mnew);
      rs += (p0 + p1) + (p2 + p3);
      short4 pk;
      pk.x = f2b(p0); pk.y = f2b(p1); pk.z = f2b(p2); pk.w = f2b(p3);
      *(short4*)&Ps[w][c][mt * 16 + 4 * g] = pk;
    }
    rs += __shfl_xor(rs, 16);
    rs += __shfl_xor(rs, 32);
    lsum = lsum * fac + rs;
    mold = mnew;
#pragma unroll
    for (int dt = 0; dt < 4; ++dt)
#pragma unroll
      for (int r = 0; r < 4; ++r) oacc[dt][r] *= fac;
    // PV: OUT^T += V^T @ P^T (P read back same-wave; compiler orders via lgkmcnt)
    bf16x8 pb[2];
#pragma unroll
    for (int ks = 0; ks < 2; ++ks)
      pb[ks] = *(const bf16x8*)&Ps[w][c][ks * 32 + g * 8];
#pragma unroll
    for (int dt = 0; dt < 4; ++dt) {
      const int row = dt * 16 + c;
#pragma unroll
      for (int ks = 0; ks < 2; ++ks) {
        bf16x8 vf = *(const bf16x8*)&Vs[row * 64 + ((ks * 32 + g * 8) ^ ((row & 7) << 3))];
        oacc[dt] = __builtin_amdgcn_mfma_f32_16x16x32_bf16(vf, pb[ks], oacc[dt], 0, 0, 0);
      }
    }
    __syncthreads();
    if (kt < qt) {
      const int k1 = (kt + 1) * 64;
      stage_sw(Ks, qkb + ((size_t)(b * T_SEQ + k1) * 3072 + 1024 + h * 64) * 2, 3072 * 2, w, l);
      stage_sw(Vs, vtb + (size_t)k1 * 2, T_SEQ * 2, w, l);
      __syncthreads();
    }
  }
  // epilogue: gate * acc / l + V residual  -> Ob bf16
  const float gh = gate[h] / lsum;
  const short* Vr = QKV + (size_t)(b * T_SEQ + q0 + w * 16 + c) * 3072 + 2048 + h * 64;
  short* Oro = Ob + (size_t)(b * T_SEQ + q0 + w * 16 + c) * 1024 + h * 64;
#pragma unroll
  for (int dt = 0; dt < 4; ++dt) {
    const int d0 = dt * 16 + 4 * g;
    short4 vres = *(const short4*)&Vr[d0];
    short4 o;
    o.x = f2b(oacc[dt][0] * gh + b2f(vres.x));
    o.y = f2b(oacc[dt][1] * gh + b2f(vres.y));
    o.z = f2b(oacc[dt][2] * gh + b2f(vres.z));
    o.w = f2b(oacc[dt][3] * gh + b2f(vres.w));
    *(short4*)&Oro[d0] = o;
  }
}

extern "C" void kernel_launch(void* const* d_in, const int* in_sizes, int n_in,
                              void* d_out, int out_size, void* d_ws, size_t ws_size,
                              hipStream_t stream) {
  const float* x  = (const float*)d_in[0];
  const float* Wq = (const float*)d_in[2];
  const float* Wk = (const float*)d_in[3];
  const float* Wv = (const float*)d_in[4];
  const float* Wo = (const float*)d_in[5];
  const float* qw = (const float*)d_in[6];
  const float* kw = (const float*)d_in[7];
  const float* gate = (const float*)d_in[8];
  float* out = (float*)d_out;

  char* ws = (char*)d_ws;
  short* xb  = (short*)ws;                        // 8 MB
  short* WT  = (short*)(ws + ((size_t)8 << 20));  // 8 MB  [4096][1024]: WqT,WkT,WvT,WoT
  short* QKV = (short*)(ws + ((size_t)16 << 20)); // 24 MB [4096][3072]
  short* VTb = (short*)(ws + ((size_t)40 << 20)); // 8 MB  [b,h,64,2048]
  short* Obf = (short*)(ws + ((size_t)48 << 20)); // 8 MB  [4096][1024]

  const int M = BATCH * T_SEQ;  // 4096

  cvt_x<<<2048, 256, 0, stream>>>(x, xb);
  transW<<<dim3(16, 16, 4), 256, 0, stream>>>(Wq, Wk, Wv, Wo, WT);
  gemm_bf16<128, false><<<dim3(24, 32), 256, 0, stream>>>(xb, WT, QKV, M, 3072, CDIM);
  rmsnorm_qk<<<(M * NHEAD) / 4, 256, 0, stream>>>(QKV, qw, kw);
  vt_kernel<<<dim3(T_SEQ / 32, NHEAD, BATCH), 256, 0, stream>>>(QKV, VTb);
  attn_fwd<<<1024, 256, 0, stream>>>(QKV, VTb, gate, Obf);
  gemm_bf16<64, true><<<dim3(16, 32), 256, 0, stream>>>(Obf, WT + (size_t)3072 * 1024, out, M, CDIM, CDIM);
}

// Round 3
// 132.558 us; speedup vs baseline: 8.9862x; 1.2337x over previous
//
#include <hip/hip_runtime.h>

#define T_SEQ 2048
#define CDIM 1024
#define NHEAD 16
#define HDIM 64
#define BATCH 2
#define EPSV 1e-5f
#define SCALE 0.125f
#define LOG2E 1.44269504088896f

typedef __attribute__((ext_vector_type(8))) short bf16x8;
typedef __attribute__((ext_vector_type(4))) float f32x4;

__device__ __forceinline__ float b2f(short s) {
  unsigned u = ((unsigned)(unsigned short)s) << 16;
  return __builtin_bit_cast(float, u);
}
__device__ __forceinline__ short f2b(float f) {
  unsigned u = __builtin_bit_cast(unsigned, f);
  unsigned r = (u + 0x7fffu + ((u >> 16) & 1u)) >> 16;
  return (short)r;
}

__device__ __forceinline__ void gld16(const void* g, void* l) {
  __builtin_amdgcn_global_load_lds((const __attribute__((address_space(1))) unsigned*)g,
                                   (__attribute__((address_space(3))) unsigned*)l, 16, 0, 0);
}

// Stage an 8 KB tile (64 rows x 128 B) global->LDS, linear LDS dest,
// pre-swizzled global source: byte-in-row ^= (row&7)<<4.
__device__ __forceinline__ void stage_sw(short* lds, const char* gbase, int gstride,
                                         int w, int l) {
#pragma unroll
  for (int i = 0; i < 2; ++i) {
    int chunk = w * 2048 + i * 1024 + l * 16;
    int row = chunk >> 7;
    int bir = chunk & 127;
    const char* src = gbase + (size_t)row * gstride + (bir ^ ((row & 7) << 4));
    gld16(src, (char*)lds + (w * 2048 + i * 1024));
  }
}

// ---------------- convert x fp32 -> bf16 ----------------
__global__ __launch_bounds__(256) void cvt_x(const float* __restrict__ x,
                                             short* __restrict__ xb) {
  size_t i = ((size_t)blockIdx.x * 256 + threadIdx.x) * 8;
  float4 a = *(const float4*)&x[i];
  float4 b = *(const float4*)&x[i + 4];
  short4 lo, hi;
  lo.x = f2b(a.x); lo.y = f2b(a.y); lo.z = f2b(a.z); lo.w = f2b(a.w);
  hi.x = f2b(b.x); hi.y = f2b(b.y); hi.z = f2b(b.z); hi.w = f2b(b.w);
  *(short4*)&xb[i] = lo;
  *(short4*)&xb[i + 4] = hi;
}

// ---------------- transpose weights fp32 [K][N] -> bf16 [N][K], combined ----------------
__global__ __launch_bounds__(256) void transW(const float* __restrict__ Wq,
                                              const float* __restrict__ Wk,
                                              const float* __restrict__ Wv,
                                              const float* __restrict__ Wo,
                                              short* __restrict__ WT) {
  __shared__ float tile[64][65];
  const int z = blockIdx.z;
  const float* W = (z == 0) ? Wq : (z == 1) ? Wk : (z == 2) ? Wv : Wo;
  const int r0 = blockIdx.y * 64, c0 = blockIdx.x * 64;
  const int tr = threadIdx.x >> 4, tc4 = (threadIdx.x & 15) * 4;
#pragma unroll
  for (int i = 0; i < 4; ++i) {
    float4 v = *(const float4*)&W[(size_t)(r0 + tr + i * 16) * 1024 + c0 + tc4];
    tile[tr + i * 16][tc4 + 0] = v.x;
    tile[tr + i * 16][tc4 + 1] = v.y;
    tile[tr + i * 16][tc4 + 2] = v.z;
    tile[tr + i * 16][tc4 + 3] = v.w;
  }
  __syncthreads();
#pragma unroll
  for (int i = 0; i < 4; ++i) {
    int n = tr + i * 16;
    short4 o;
    o.x = f2b(tile[tc4 + 0][n]);
    o.y = f2b(tile[tc4 + 1][n]);
    o.z = f2b(tile[tc4 + 2][n]);
    o.w = f2b(tile[tc4 + 3][n]);
    *(short4*)&WT[((size_t)(z * 1024) + c0 + n) * 1024 + r0 + tc4] = o;
  }
}

// ---------------- bf16 MFMA GEMM: C[M,N] = A[M,K] @ Bt[N,K]^T ----------------
// BM=128, BK=32, 256 threads (4 waves 2x2), 2-phase double-buffered staging.
// NORM: fuse per-head (64-col) RMSNorm on Q (cols<1024, + SCALE*LOG2E) and K
// (1024<=cols<2048) into the epilogue.
template <int BN, bool F32OUT, bool NORM>
__global__ __launch_bounds__(256) void gemm_bf16(const short* __restrict__ A,
                                                 const short* __restrict__ Bt,
                                                 void* __restrict__ Cv,
                                                 const float* __restrict__ qw,
                                                 const float* __restrict__ kw,
                                                 int M, int N, int K) {
  constexpr int NFR = BN / 32;
  __shared__ __attribute__((aligned(16))) short As[2][128 * 32];
  __shared__ __attribute__((aligned(16))) short Bs[2][BN * 32];
  const int tid = threadIdx.x;
  const int w = tid >> 6, l = tid & 63;
  const int g = l >> 4, c = l & 15;
  const int wm = w >> 1, wn = w & 1;
  const int m0 = blockIdx.y * 128, n0 = blockIdx.x * BN;
  const char* Ab = (const char*)A;
  const char* Bb = (const char*)Bt;

  auto stage = [&](int k0, int buf) {
#pragma unroll
    for (int i = 0; i < 2; ++i) {
      int chunk = w * 2048 + i * 1024 + l * 16;
      int row = chunk >> 6, bir = chunk & 63;
      gld16(Ab + ((size_t)(m0 + row) * K + k0) * 2 + bir,
            (char*)As[buf] + (w * 2048 + i * 1024));
    }
#pragma unroll
    for (int i = 0; i < BN / 64; ++i) {
      int chunk = w * (BN * 16) + i * 1024 + l * 16;
      int row = chunk >> 6, bir = chunk & 63;
      gld16(Bb + ((size_t)(n0 + row) * K + k0) * 2 + bir,
            (char*)Bs[buf] + (w * (BN * 16) + i * 1024));
    }
  };

  f32x4 acc[4][NFR];
#pragma unroll
  for (int mt = 0; mt < 4; ++mt)
#pragma unroll
    for (int nt = 0; nt < NFR; ++nt) {
      f32x4 z = {0.f, 0.f, 0.f, 0.f};
      acc[mt][nt] = z;
    }

  stage(0, 0);
  __syncthreads();
  int cur = 0;
  for (int k0 = 0; k0 < K; k0 += 32) {
    if (k0 + 32 < K) stage(k0 + 32, cur ^ 1);
    bf16x8 a[4], bf[NFR];
#pragma unroll
    for (int mt = 0; mt < 4; ++mt)
      a[mt] = *(const bf16x8*)&As[cur][(wm * 64 + mt * 16 + c) * 32 + g * 8];
#pragma unroll
    for (int nt = 0; nt < NFR; ++nt)
      bf[nt] = *(const bf16x8*)&Bs[cur][(wn * (BN / 2) + nt * 16 + c) * 32 + g * 8];
#pragma unroll
    for (int mt = 0; mt < 4; ++mt)
#pragma unroll
      for (int nt = 0; nt < NFR; ++nt)
        acc[mt][nt] = __builtin_amdgcn_mfma_f32_16x16x32_bf16(a[mt], bf[nt], acc[mt][nt], 0, 0, 0);
    __syncthreads();
    cur ^= 1;
  }

  if constexpr (NORM) {
    if (n0 < 2048) {
      const float* wgt = (n0 < 1024) ? qw : kw;
      const float scl = (n0 < 1024) ? SCALE * LOG2E : 1.f;
      float w4[NFR];
#pragma unroll
      for (int nt = 0; nt < NFR; ++nt) w4[nt] = wgt[nt * 16 + c] * scl;
#pragma unroll
      for (int mt = 0; mt < 4; ++mt)
#pragma unroll
        for (int r = 0; r < 4; ++r) {
          float s = 0.f;
#pragma unroll
          for (int nt = 0; nt < NFR; ++nt) s += acc[mt][nt][r] * acc[mt][nt][r];
          s += __shfl_xor(s, 1);
          s += __shfl_xor(s, 2);
          s += __shfl_xor(s, 4);
          s += __shfl_xor(s, 8);
          const float rstd = rsqrtf(s * (1.0f / 64.0f) + EPSV);
#pragma unroll
          for (int nt = 0; nt < NFR; ++nt) acc[mt][nt][r] *= rstd * w4[nt];
        }
    }
  }

  if constexpr (F32OUT) {
    float* C = (float*)Cv;
#pragma unroll
    for (int mt = 0; mt < 4; ++mt)
#pragma unroll
      for (int nt = 0; nt < NFR; ++nt)
#pragma unroll
        for (int r = 0; r < 4; ++r)
          C[(size_t)(m0 + wm * 64 + mt * 16 + 4 * g + r) * N + n0 + wn * (BN / 2) + nt * 16 + c] =
              acc[mt][nt][r];
  } else {
    short* C = (short*)Cv;
#pragma unroll
    for (int mt = 0; mt < 4; ++mt)
#pragma unroll
      for (int nt = 0; nt < NFR; ++nt)
#pragma unroll
        for (int r = 0; r < 4; ++r)
          C[(size_t)(m0 + wm * 64 + mt * 16 + 4 * g + r) * N + n0 + wn * (BN / 2) + nt * 16 + c] =
              f2b(acc[mt][nt][r]);
  }
}

// ---------------- V transpose: QKV's V slice [t][h*64+d] -> VT [b,h,d,t] ----------------
__global__ __launch_bounds__(256) void vt_kernel(const short* __restrict__ QKV,
                                                 short* __restrict__ VT) {
  const int w = threadIdx.x >> 6, l = threadIdx.x & 63;
  const int t0 = blockIdx.x * 32 + w * 8;
  const int h = blockIdx.y, b = blockIdx.z;
  short v[8];
#pragma unroll
  for (int j = 0; j < 8; ++j)
    v[j] = QKV[(size_t)(b * T_SEQ + t0 + j) * 3072 + 2048 + h * 64 + l];
  short* dst = VT + ((size_t)(b * NHEAD + h) * 64 + l) * T_SEQ + t0;
  *(bf16x8*)dst = *(bf16x8*)v;
}

// ---------------- MFMA flash attention ----------------
// 512 blocks; block = (b,h, paired q-tiles {31-p, p}) -> uniform 33 k-tile iters.
// 4 waves; S^T = K@Q^T (wave w owns q-cols w*16..+15); scores in log2 units
// (LOG2E folded into Q norm); K/V double-buffered, staged issue-early.
__global__ __launch_bounds__(256) void attn_fwd(const short* __restrict__ QKV,
                                                const short* __restrict__ VT,
                                                const float* __restrict__ gate,
                                                short* __restrict__ Ob) {
  __shared__ __attribute__((aligned(16))) short Qs[64 * 64];
  __shared__ __attribute__((aligned(16))) short Ks[2][64 * 64];
  __shared__ __attribute__((aligned(16))) short Vs[2][64 * 64];
  __shared__ __attribute__((aligned(16))) short Ps[4][16][72];

  const int bid = blockIdx.x;
  const int L = (bid & 7) * 64 + (bid >> 3);  // XCD-chunked: 4 bh per XCD
  const int bh = L >> 4, p = L & 15;
  const int h = bh & 15, b = bh >> 4;
  const int tid = threadIdx.x;
  const int w = tid >> 6, l = tid & 63;
  const int g = l >> 4, c = l & 15;

  const char* qkb = (const char*)QKV;
  const char* kbase = qkb + ((size_t)(b * T_SEQ) * 3072 + 1024 + h * 64) * 2;
  const char* vtb = (const char*)VT + ((size_t)(b * NHEAD + h) * 64) * T_SEQ * 2;
  const float gh = gate[h];

  const int qts[2] = {31 - p, p};
#pragma unroll 1
  for (int pass = 0; pass < 2; ++pass) {
    const int qt = qts[pass];
    const int q0 = qt * 64;

    stage_sw(Qs, qkb + ((size_t)(b * T_SEQ + q0) * 3072 + h * 64) * 2, 3072 * 2, w, l);
    stage_sw(Ks[0], kbase, 3072 * 2, w, l);
    stage_sw(Vs[0], vtb, T_SEQ * 2, w, l);
    __syncthreads();

    bf16x8 qf[2];
    {
      const int row = w * 16 + c;
#pragma unroll
      for (int ks = 0; ks < 2; ++ks)
        qf[ks] = *(const bf16x8*)&Qs[row * 64 + ((ks * 32 + g * 8) ^ ((row & 7) << 3))];
    }

    f32x4 oacc[4];
#pragma unroll
    for (int dt = 0; dt < 4; ++dt) {
      f32x4 z = {0.f, 0.f, 0.f, 0.f};
      oacc[dt] = z;
    }
    float mold = -1e30f, lsum = 0.f;
    int cur = 0;

    for (int kt = 0; kt <= qt; ++kt) {
      if (kt < qt) {  // issue next-tile staging first (latency hides under compute)
        stage_sw(Ks[cur ^ 1], kbase + (size_t)(kt + 1) * 64 * 3072 * 2, 3072 * 2, w, l);
        stage_sw(Vs[cur ^ 1], vtb + (size_t)(kt + 1) * 64 * 2, T_SEQ * 2, w, l);
      }
      f32x4 sacc[4];
#pragma unroll
      for (int mt = 0; mt < 4; ++mt) {
        f32x4 z = {0.f, 0.f, 0.f, 0.f};
        sacc[mt] = z;
      }
#pragma unroll
      for (int mt = 0; mt < 4; ++mt) {
        const int row = mt * 16 + c;
#pragma unroll
        for (int ks = 0; ks < 2; ++ks) {
          bf16x8 kf = *(const bf16x8*)&Ks[cur][row * 64 + ((ks * 32 + g * 8) ^ ((row & 7) << 3))];
          sacc[mt] = __builtin_amdgcn_mfma_f32_16x16x32_bf16(kf, qf[ks], sacc[mt], 0, 0, 0);
        }
      }
      // hoist V fragment reads (overlap with softmax VALU)
      bf16x8 vf[4][2];
#pragma unroll
      for (int dt = 0; dt < 4; ++dt) {
        const int row = dt * 16 + c;
#pragma unroll
        for (int ks = 0; ks < 2; ++ks)
          vf[dt][ks] = *(const bf16x8*)&Vs[cur][row * 64 + ((ks * 32 + g * 8) ^ ((row & 7) << 3))];
      }
      if (kt == qt) {  // diagonal causal mask
#pragma unroll
        for (int mt = 0; mt < 4; ++mt)
#pragma unroll
          for (int r = 0; r < 4; ++r)
            if (mt * 16 + 4 * g + r > w * 16 + c) sacc[mt][r] = -1e30f;
      }
      // online softmax in log2 units
      float m4[4];
#pragma unroll
      for (int mt = 0; mt < 4; ++mt)
        m4[mt] = fmaxf(fmaxf(sacc[mt][0], sacc[mt][1]), fmaxf(sacc[mt][2], sacc[mt][3]));
      float tm = fmaxf(fmaxf(m4[0], m4[1]), fmaxf(m4[2], m4[3]));
      tm = fmaxf(tm, __shfl_xor(tm, 16));
      tm = fmaxf(tm, __shfl_xor(tm, 32));
      float mnew, fac;
      if (__all(tm <= mold + 11.5f)) {  // defer-max (T13): skip O rescale
        mnew = mold;
        fac = 1.f;
      } else {
        mnew = fmaxf(mold, tm);
        fac = exp2f(mold - mnew);
#pragma unroll
        for (int dt = 0; dt < 4; ++dt)
#pragma unroll
          for (int r = 0; r < 4; ++r) oacc[dt][r] *= fac;
      }
      float rs = 0.f;
#pragma unroll
      for (int mt = 0; mt < 4; ++mt) {
        float p0 = exp2f(sacc[mt][0] - mnew);
        float p1 = exp2f(sacc[mt][1] - mnew);
        float p2 = exp2f(sacc[mt][2] - mnew);
        float p3 = exp2f(sacc[mt][3] - mnew);
        rs += (p0 + p1) + (p2 + p3);
        short4 pk;
        pk.x = f2b(p0); pk.y = f2b(p1); pk.z = f2b(p2); pk.w = f2b(p3);
        *(short4*)&Ps[w][c][mt * 16 + 4 * g] = pk;
      }
      rs += __shfl_xor(rs, 16);
      rs += __shfl_xor(rs, 32);
      lsum = lsum * fac + rs;
      mold = mnew;
      bf16x8 pb[2];
#pragma unroll
      for (int ks = 0; ks < 2; ++ks)
        pb[ks] = *(const bf16x8*)&Ps[w][c][ks * 32 + g * 8];
#pragma unroll
      for (int dt = 0; dt < 4; ++dt)
#pragma unroll
        for (int ks = 0; ks < 2; ++ks)
          oacc[dt] = __builtin_amdgcn_mfma_f32_16x16x32_bf16(vf[dt][ks], pb[ks], oacc[dt], 0, 0, 0);
      __syncthreads();
      cur ^= 1;
    }
    // epilogue: gate/l, value residual
    const float gl = gh / lsum;
    const short* Vr = QKV + (size_t)(b * T_SEQ + q0 + w * 16 + c) * 3072 + 2048 + h * 64;
    short* Oro = Ob + (size_t)(b * T_SEQ + q0 + w * 16 + c) * 1024 + h * 64;
#pragma unroll
    for (int dt = 0; dt < 4; ++dt) {
      const int d0 = dt * 16 + 4 * g;
      short4 vres = *(const short4*)&Vr[d0];
      short4 o;
      o.x = f2b(oacc[dt][0] * gl + b2f(vres.x));
      o.y = f2b(oacc[dt][1] * gl + b2f(vres.y));
      o.z = f2b(oacc[dt][2] * gl + b2f(vres.z));
      o.w = f2b(oacc[dt][3] * gl + b2f(vres.w));
      *(short4*)&Oro[d0] = o;
    }
  }
}

extern "C" void kernel_launch(void* const* d_in, const int* in_sizes, int n_in,
                              void* d_out, int out_size, void* d_ws, size_t ws_size,
                              hipStream_t stream) {
  const float* x  = (const float*)d_in[0];
  const float* Wq = (const float*)d_in[2];
  const float* Wk = (const float*)d_in[3];
  const float* Wv = (const float*)d_in[4];
  const float* Wo = (const float*)d_in[5];
  const float* qw = (const float*)d_in[6];
  const float* kw = (const float*)d_in[7];
  const float* gate = (const float*)d_in[8];
  float* out = (float*)d_out;

  char* ws = (char*)d_ws;
  short* xb  = (short*)ws;                        // 8 MB
  short* WT  = (short*)(ws + ((size_t)8 << 20));  // 8 MB  [4096][1024]: WqT,WkT,WvT,WoT
  short* QKV = (short*)(ws + ((size_t)16 << 20)); // 24 MB [4096][3072]
  short* VTb = (short*)(ws + ((size_t)40 << 20)); // 8 MB  [b,h,64,2048]
  short* Obf = (short*)(ws + ((size_t)48 << 20)); // 8 MB  [4096][1024]

  const int M = BATCH * T_SEQ;  // 4096

  cvt_x<<<2048, 256, 0, stream>>>(x, xb);
  transW<<<dim3(16, 16, 4), 256, 0, stream>>>(Wq, Wk, Wv, Wo, WT);
  gemm_bf16<128, false, true><<<dim3(24, 32), 256, 0, stream>>>(xb, WT, QKV, qw, kw, M, 3072, CDIM);
  vt_kernel<<<dim3(T_SEQ / 32, NHEAD, BATCH), 256, 0, stream>>>(QKV, VTb);
  attn_fwd<<<512, 256, 0, stream>>>(QKV, VTb, gate, Obf);
  gemm_bf16<64, true, false><<<dim3(16, 32), 256, 0, stream>>>(Obf, WT + (size_t)3072 * 1024, out, nullptr, nullptr, M, CDIM, CDIM);
}

// Round 4
// 125.755 us; speedup vs baseline: 9.4723x; 1.0541x over previous
//
#include <hip/hip_runtime.h>

#define T_SEQ 2048
#define CDIM 1024
#define NHEAD 16
#define HDIM 64
#define BATCH 2
#define EPSV 1e-5f
#define SCALE 0.125f
#define LOG2E 1.44269504088896f

typedef __attribute__((ext_vector_type(8))) short bf16x8;
typedef __attribute__((ext_vector_type(4))) float f32x4;

__device__ __forceinline__ float b2f(short s) {
  unsigned u = ((unsigned)(unsigned short)s) << 16;
  return __builtin_bit_cast(float, u);
}
__device__ __forceinline__ short f2b(float f) {
  unsigned u = __builtin_bit_cast(unsigned, f);
  unsigned r = (u + 0x7fffu + ((u >> 16) & 1u)) >> 16;
  return (short)r;
}
__device__ __forceinline__ unsigned cvt_pk_bf16(float a, float b) {
  unsigned r;
  asm("v_cvt_pk_bf16_f32 %0, %1, %2" : "=v"(r) : "v"(a), "v"(b));
  return r;
}

__device__ __forceinline__ void gld16(const void* g, void* l) {
  __builtin_amdgcn_global_load_lds((const __attribute__((address_space(1))) unsigned*)g,
                                   (__attribute__((address_space(3))) unsigned*)l, 16, 0, 0);
}

// Stage an 8 KB tile (64 rows x 128 B) global->LDS, linear LDS dest,
// pre-swizzled global source: byte-in-row ^= (row&7)<<4.
__device__ __forceinline__ void stage_sw(short* lds, const char* gbase, int gstride,
                                         int w, int l) {
#pragma unroll
  for (int i = 0; i < 2; ++i) {
    int chunk = w * 2048 + i * 1024 + l * 16;
    int row = chunk >> 7;
    int bir = chunk & 127;
    const char* src = gbase + (size_t)row * gstride + (bir ^ ((row & 7) << 4));
    gld16(src, (char*)lds + (w * 2048 + i * 1024));
  }
}

// ---------------- convert x fp32 -> bf16 ----------------
__global__ __launch_bounds__(256) void cvt_x(const float* __restrict__ x,
                                             short* __restrict__ xb) {
  size_t i = ((size_t)blockIdx.x * 256 + threadIdx.x) * 8;
  float4 a = *(const float4*)&x[i];
  float4 b = *(const float4*)&x[i + 4];
  short4 lo, hi;
  lo.x = f2b(a.x); lo.y = f2b(a.y); lo.z = f2b(a.z); lo.w = f2b(a.w);
  hi.x = f2b(b.x); hi.y = f2b(b.y); hi.z = f2b(b.z); hi.w = f2b(b.w);
  *(short4*)&xb[i] = lo;
  *(short4*)&xb[i + 4] = hi;
}

// ---------------- transpose weights fp32 [K][N] -> bf16 [N][K], combined ----------------
__global__ __launch_bounds__(256) void transW(const float* __restrict__ Wq,
                                              const float* __restrict__ Wk,
                                              const float* __restrict__ Wv,
                                              const float* __restrict__ Wo,
                                              short* __restrict__ WT) {
  __shared__ float tile[64][65];
  const int z = blockIdx.z;
  const float* W = (z == 0) ? Wq : (z == 1) ? Wk : (z == 2) ? Wv : Wo;
  const int r0 = blockIdx.y * 64, c0 = blockIdx.x * 64;
  const int tr = threadIdx.x >> 4, tc4 = (threadIdx.x & 15) * 4;
#pragma unroll
  for (int i = 0; i < 4; ++i) {
    float4 v = *(const float4*)&W[(size_t)(r0 + tr + i * 16) * 1024 + c0 + tc4];
    tile[tr + i * 16][tc4 + 0] = v.x;
    tile[tr + i * 16][tc4 + 1] = v.y;
    tile[tr + i * 16][tc4 + 2] = v.z;
    tile[tr + i * 16][tc4 + 3] = v.w;
  }
  __syncthreads();
#pragma unroll
  for (int i = 0; i < 4; ++i) {
    int n = tr + i * 16;
    short4 o;
    o.x = f2b(tile[tc4 + 0][n]);
    o.y = f2b(tile[tc4 + 1][n]);
    o.z = f2b(tile[tc4 + 2][n]);
    o.w = f2b(tile[tc4 + 3][n]);
    *(short4*)&WT[((size_t)(z * 1024) + c0 + n) * 1024 + r0 + tc4] = o;
  }
}

// ---------------- bf16 MFMA GEMM: C[M,N] = A[M,K] @ Bt[N,K]^T ----------------
// BM=128, BK=32, 256 threads (4 waves 2x2), 2-phase double-buffered staging.
// NORM: fuse per-head (64-col) RMSNorm on Q (cols<1024, + SCALE*LOG2E) and K
// (1024<=cols<2048) into the epilogue.
template <int BN, bool F32OUT, bool NORM>
__global__ __launch_bounds__(256) void gemm_bf16(const short* __restrict__ A,
                                                 const short* __restrict__ Bt,
                                                 void* __restrict__ Cv,
                                                 const float* __restrict__ qw,
                                                 const float* __restrict__ kw,
                                                 int M, int N, int K) {
  constexpr int NFR = BN / 32;
  __shared__ __attribute__((aligned(16))) short As[2][128 * 32];
  __shared__ __attribute__((aligned(16))) short Bs[2][BN * 32];
  const int tid = threadIdx.x;
  const int w = tid >> 6, l = tid & 63;
  const int g = l >> 4, c = l & 15;
  const int wm = w >> 1, wn = w & 1;
  const int m0 = blockIdx.y * 128, n0 = blockIdx.x * BN;
  const char* Ab = (const char*)A;
  const char* Bb = (const char*)Bt;

  auto stage = [&](int k0, int buf) {
#pragma unroll
    for (int i = 0; i < 2; ++i) {
      int chunk = w * 2048 + i * 1024 + l * 16;
      int row = chunk >> 6, bir = chunk & 63;
      gld16(Ab + ((size_t)(m0 + row) * K + k0) * 2 + bir,
            (char*)As[buf] + (w * 2048 + i * 1024));
    }
#pragma unroll
    for (int i = 0; i < BN / 64; ++i) {
      int chunk = w * (BN * 16) + i * 1024 + l * 16;
      int row = chunk >> 6, bir = chunk & 63;
      gld16(Bb + ((size_t)(n0 + row) * K + k0) * 2 + bir,
            (char*)Bs[buf] + (w * (BN * 16) + i * 1024));
    }
  };

  f32x4 acc[4][NFR];
#pragma unroll
  for (int mt = 0; mt < 4; ++mt)
#pragma unroll
    for (int nt = 0; nt < NFR; ++nt) {
      f32x4 z = {0.f, 0.f, 0.f, 0.f};
      acc[mt][nt] = z;
    }

  stage(0, 0);
  __syncthreads();
  int cur = 0;
  for (int k0 = 0; k0 < K; k0 += 32) {
    if (k0 + 32 < K) stage(k0 + 32, cur ^ 1);
    bf16x8 a[4], bf[NFR];
#pragma unroll
    for (int mt = 0; mt < 4; ++mt)
      a[mt] = *(const bf16x8*)&As[cur][(wm * 64 + mt * 16 + c) * 32 + g * 8];
#pragma unroll
    for (int nt = 0; nt < NFR; ++nt)
      bf[nt] = *(const bf16x8*)&Bs[cur][(wn * (BN / 2) + nt * 16 + c) * 32 + g * 8];
#pragma unroll
    for (int mt = 0; mt < 4; ++mt)
#pragma unroll
      for (int nt = 0; nt < NFR; ++nt)
        acc[mt][nt] = __builtin_amdgcn_mfma_f32_16x16x32_bf16(a[mt], bf[nt], acc[mt][nt], 0, 0, 0);
    __syncthreads();
    cur ^= 1;
  }

  if constexpr (NORM) {
    if (n0 < 2048) {
      const float* wgt = (n0 < 1024) ? qw : kw;
      const float scl = (n0 < 1024) ? SCALE * LOG2E : 1.f;
      float w4[NFR];
#pragma unroll
      for (int nt = 0; nt < NFR; ++nt) w4[nt] = wgt[nt * 16 + c] * scl;
#pragma unroll
      for (int mt = 0; mt < 4; ++mt)
#pragma unroll
        for (int r = 0; r < 4; ++r) {
          float s = 0.f;
#pragma unroll
          for (int nt = 0; nt < NFR; ++nt) s += acc[mt][nt][r] * acc[mt][nt][r];
          s += __shfl_xor(s, 1);
          s += __shfl_xor(s, 2);
          s += __shfl_xor(s, 4);
          s += __shfl_xor(s, 8);
          const float rstd = rsqrtf(s * (1.0f / 64.0f) + EPSV);
#pragma unroll
          for (int nt = 0; nt < NFR; ++nt) acc[mt][nt][r] *= rstd * w4[nt];
        }
    }
  }

  if constexpr (F32OUT) {
    float* C = (float*)Cv;
#pragma unroll
    for (int mt = 0; mt < 4; ++mt)
#pragma unroll
      for (int nt = 0; nt < NFR; ++nt)
#pragma unroll
        for (int r = 0; r < 4; ++r)
          C[(size_t)(m0 + wm * 64 + mt * 16 + 4 * g + r) * N + n0 + wn * (BN / 2) + nt * 16 + c] =
              acc[mt][nt][r];
  } else {
    short* C = (short*)Cv;
#pragma unroll
    for (int mt = 0; mt < 4; ++mt)
#pragma unroll
      for (int nt = 0; nt < NFR; ++nt)
#pragma unroll
        for (int r = 0; r < 4; ++r)
          C[(size_t)(m0 + wm * 64 + mt * 16 + 4 * g + r) * N + n0 + wn * (BN / 2) + nt * 16 + c] =
              f2b(acc[mt][nt][r]);
  }
}

// ---------------- V transpose: QKV's V slice [t][h*64+d] -> VT [b,h,d,t] ----------------
__global__ __launch_bounds__(256) void vt_kernel(const short* __restrict__ QKV,
                                                 short* __restrict__ VT) {
  const int w = threadIdx.x >> 6, l = threadIdx.x & 63;
  const int t0 = blockIdx.x * 32 + w * 8;
  const int h = blockIdx.y, b = blockIdx.z;
  short v[8];
#pragma unroll
  for (int j = 0; j < 8; ++j)
    v[j] = QKV[(size_t)(b * T_SEQ + t0 + j) * 3072 + 2048 + h * 64 + l];
  short* dst = VT + ((size_t)(b * NHEAD + h) * 64 + l) * T_SEQ + t0;
  *(bf16x8*)dst = *(bf16x8*)v;
}

// ---------------- MFMA flash attention ----------------
// 1024 blocks, one (b,h,qt) each; 3 blocks/CU (LDS 49 KB). Dispatch order:
// qt descending (big first), bid&7 = XCD chunk holding 4 bh (K/V L2-resident).
// 4 waves; S^T = K@Q^T (wave w owns q-cols w*16..+15); scores in log2 units;
// K/V double-buffered, issue-early staging; cvt_pk P pack; setprio on MFMA.
__global__ __launch_bounds__(256) void attn_fwd(const short* __restrict__ QKV,
                                                const short* __restrict__ VT,
                                                const float* __restrict__ gate,
                                                short* __restrict__ Ob) {
  __shared__ __attribute__((aligned(16))) short Qs[64 * 64];
  __shared__ __attribute__((aligned(16))) short Ks[2][64 * 64];
  __shared__ __attribute__((aligned(16))) short Vs[2][64 * 64];
  __shared__ __attribute__((aligned(16))) short Ps[4][16][72];

  const int bid = blockIdx.x;
  const int xcd = bid & 7, s = bid >> 3;
  const int qt = 31 - (s >> 2);
  const int bh = xcd * 4 + (s & 3);
  const int h = bh & 15, b = bh >> 4;
  const int q0 = qt * 64;
  const int tid = threadIdx.x;
  const int w = tid >> 6, l = tid & 63;
  const int g = l >> 4, c = l & 15;

  const char* qkb = (const char*)QKV;
  const char* kbase = qkb + ((size_t)(b * T_SEQ) * 3072 + 1024 + h * 64) * 2;
  const char* vtb = (const char*)VT + ((size_t)(b * NHEAD + h) * 64) * T_SEQ * 2;
  const float gh = gate[h];

  stage_sw(Qs, qkb + ((size_t)(b * T_SEQ + q0) * 3072 + h * 64) * 2, 3072 * 2, w, l);
  stage_sw(Ks[0], kbase, 3072 * 2, w, l);
  stage_sw(Vs[0], vtb, T_SEQ * 2, w, l);
  __syncthreads();

  bf16x8 qf[2];
  {
    const int row = w * 16 + c;
#pragma unroll
    for (int ks = 0; ks < 2; ++ks)
      qf[ks] = *(const bf16x8*)&Qs[row * 64 + ((ks * 32 + g * 8) ^ ((row & 7) << 3))];
  }

  f32x4 oacc[4];
#pragma unroll
  for (int dt = 0; dt < 4; ++dt) {
    f32x4 z = {0.f, 0.f, 0.f, 0.f};
    oacc[dt] = z;
  }
  float mold = -1e30f, lsum = 0.f;
  int cur = 0;

  for (int kt = 0; kt <= qt; ++kt) {
    if (kt < qt) {  // issue next-tile staging first (latency hides under compute)
      stage_sw(Ks[cur ^ 1], kbase + (size_t)(kt + 1) * 64 * 3072 * 2, 3072 * 2, w, l);
      stage_sw(Vs[cur ^ 1], vtb + (size_t)(kt + 1) * 64 * 2, T_SEQ * 2, w, l);
    }
    f32x4 sacc[4];
#pragma unroll
    for (int mt = 0; mt < 4; ++mt) {
      f32x4 z = {0.f, 0.f, 0.f, 0.f};
      sacc[mt] = z;
    }
    __builtin_amdgcn_s_setprio(1);
#pragma unroll
    for (int mt = 0; mt < 4; ++mt) {
      const int row = mt * 16 + c;
#pragma unroll
      for (int ks = 0; ks < 2; ++ks) {
        bf16x8 kf = *(const bf16x8*)&Ks[cur][row * 64 + ((ks * 32 + g * 8) ^ ((row & 7) << 3))];
        sacc[mt] = __builtin_amdgcn_mfma_f32_16x16x32_bf16(kf, qf[ks], sacc[mt], 0, 0, 0);
      }
    }
    __builtin_amdgcn_s_setprio(0);
    // hoist V fragment reads (overlap with softmax VALU)
    bf16x8 vf[4][2];
#pragma unroll
    for (int dt = 0; dt < 4; ++dt) {
      const int row = dt * 16 + c;
#pragma unroll
      for (int ks = 0; ks < 2; ++ks)
        vf[dt][ks] = *(const bf16x8*)&Vs[cur][row * 64 + ((ks * 32 + g * 8) ^ ((row & 7) << 3))];
    }
    if (kt == qt) {  // diagonal causal mask
#pragma unroll
      for (int mt = 0; mt < 4; ++mt)
#pragma unroll
        for (int r = 0; r < 4; ++r)
          if (mt * 16 + 4 * g + r > w * 16 + c) sacc[mt][r] = -1e30f;
    }
    // online softmax in log2 units
    float m4[4];
#pragma unroll
    for (int mt = 0; mt < 4; ++mt)
      m4[mt] = fmaxf(fmaxf(sacc[mt][0], sacc[mt][1]), fmaxf(sacc[mt][2], sacc[mt][3]));
    float tm = fmaxf(fmaxf(m4[0], m4[1]), fmaxf(m4[2], m4[3]));
    tm = fmaxf(tm, __shfl_xor(tm, 16));
    tm = fmaxf(tm, __shfl_xor(tm, 32));
    float mnew, fac;
    if (__all(tm <= mold + 11.5f)) {  // defer-max (T13): skip O rescale
      mnew = mold;
      fac = 1.f;
    } else {
      mnew = fmaxf(mold, tm);
      fac = exp2f(mold - mnew);
#pragma unroll
      for (int dt = 0; dt < 4; ++dt)
#pragma unroll
        for (int r = 0; r < 4; ++r) oacc[dt][r] *= fac;
    }
    float rsm[4];
#pragma unroll
    for (int mt = 0; mt < 4; ++mt) {
      float p0 = exp2f(sacc[mt][0] - mnew);
      float p1 = exp2f(sacc[mt][1] - mnew);
      float p2 = exp2f(sacc[mt][2] - mnew);
      float p3 = exp2f(sacc[mt][3] - mnew);
      rsm[mt] = (p0 + p1) + (p2 + p3);
      uint2 pk;
      pk.x = cvt_pk_bf16(p0, p1);
      pk.y = cvt_pk_bf16(p2, p3);
      *(uint2*)&Ps[w][c][mt * 16 + 4 * g] = pk;
    }
    float rs = (rsm[0] + rsm[1]) + (rsm[2] + rsm[3]);
    rs += __shfl_xor(rs, 16);
    rs += __shfl_xor(rs, 32);
    lsum = lsum * fac + rs;
    mold = mnew;
    bf16x8 pb[2];
#pragma unroll
    for (int ks = 0; ks < 2; ++ks)
      pb[ks] = *(const bf16x8*)&Ps[w][c][ks * 32 + g * 8];
    __builtin_amdgcn_s_setprio(1);
#pragma unroll
    for (int dt = 0; dt < 4; ++dt)
#pragma unroll
      for (int ks = 0; ks < 2; ++ks)
        oacc[dt] = __builtin_amdgcn_mfma_f32_16x16x32_bf16(vf[dt][ks], pb[ks], oacc[dt], 0, 0, 0);
    __builtin_amdgcn_s_setprio(0);
    __syncthreads();
    cur ^= 1;
  }
  // epilogue: gate/l, value residual
  const float gl = gh / lsum;
  const short* Vr = QKV + (size_t)(b * T_SEQ + q0 + w * 16 + c) * 3072 + 2048 + h * 64;
  short* Oro = Ob + (size_t)(b * T_SEQ + q0 + w * 16 + c) * 1024 + h * 64;
#pragma unroll
  for (int dt = 0; dt < 4; ++dt) {
    const int d0 = dt * 16 + 4 * g;
    short4 vres = *(const short4*)&Vr[d0];
    short4 o;
    o.x = f2b(oacc[dt][0] * gl + b2f(vres.x));
    o.y = f2b(oacc[dt][1] * gl + b2f(vres.y));
    o.z = f2b(oacc[dt][2] * gl + b2f(vres.z));
    o.w = f2b(oacc[dt][3] * gl + b2f(vres.w));
    *(short4*)&Oro[d0] = o;
  }
}

extern "C" void kernel_launch(void* const* d_in, const int* in_sizes, int n_in,
                              void* d_out, int out_size, void* d_ws, size_t ws_size,
                              hipStream_t stream) {
  const float* x  = (const float*)d_in[0];
  const float* Wq = (const float*)d_in[2];
  const float* Wk = (const float*)d_in[3];
  const float* Wv = (const float*)d_in[4];
  const float* Wo = (const float*)d_in[5];
  const float* qw = (const float*)d_in[6];
  const float* kw = (const float*)d_in[7];
  const float* gate = (const float*)d_in[8];
  float* out = (float*)d_out;

  char* ws = (char*)d_ws;
  short* xb  = (short*)ws;                        // 8 MB
  short* WT  = (short*)(ws + ((size_t)8 << 20));  // 8 MB  [4096][1024]: WqT,WkT,WvT,WoT
  short* QKV = (short*)(ws + ((size_t)16 << 20)); // 24 MB [4096][3072]
  short* VTb = (short*)(ws + ((size_t)40 << 20)); // 8 MB  [b,h,64,2048]
  short* Obf = (short*)(ws + ((size_t)48 << 20)); // 8 MB  [4096][1024]

  const int M = BATCH * T_SEQ;  // 4096

  cvt_x<<<2048, 256, 0, stream>>>(x, xb);
  transW<<<dim3(16, 16, 4), 256, 0, stream>>>(Wq, Wk, Wv, Wo, WT);
  gemm_bf16<128, false, true><<<dim3(24, 32), 256, 0, stream>>>(xb, WT, QKV, qw, kw, M, 3072, CDIM);
  vt_kernel<<<dim3(T_SEQ / 32, NHEAD, BATCH), 256, 0, stream>>>(QKV, VTb);
  attn_fwd<<<1024, 256, 0, stream>>>(QKV, VTb, gate, Obf);
  gemm_bf16<128, true, false><<<dim3(8, 32), 256, 0, stream>>>(Obf, WT + (size_t)3072 * 1024, out, nullptr, nullptr, M, CDIM, CDIM);
}